// Round 3
// baseline (103.150 us; speedup 1.0000x reference)
//
#include <hip/hip_runtime.h>
#include <hip/hip_cooperative_groups.h>
#include <math.h>

namespace cg = cooperative_groups;

#define B_ROWS 1024
#define D_DIM 128
#define DCHUNKS 32  // float4 chunks per row
#define NBLOCKS (B_ROWS / 4)

__device__ __forceinline__ float dot4(float4 a, float4 b) {
  return fmaf(a.x, b.x, fmaf(a.y, b.y, fmaf(a.z, b.z, a.w * b.w)));
}

// kC = 0.05, sqrt(c) = 0.223606..., 2/sqrt(c)*atanh -> (1/sqrt(c))*log form
// TEMP = 0.1, ALPHA_D = 0.5 -> comb = 5 * (cos_sim - dist)
#define K_C 0.05f
#define K_SQRT_C 0.22360679774997896f
#define K_INV_SQRT_C 4.47213595499958f
#define K_EPS 1e-6f
#define K_HALF_INV_T 5.0f

__global__ __launch_bounds__(1024) void hypcd_pair(const float* __restrict__ za,
                                                   const float* __restrict__ zb,
                                                   float* __restrict__ partials,
                                                   float* __restrict__ out) {
  __shared__ float s_a[4 * D_DIM];
  __shared__ float s_x2[4];
  __shared__ float s_pos[4];
  __shared__ float s_esum[4];
  __shared__ float s_rl[4];

  const int tid = threadIdx.x;
  const int i0 = blockIdx.x * 4;

  // stage the block's 4 A-rows (512 floats = 128 float4), coalesced
  if (tid < (4 * D_DIM / 4)) {
    reinterpret_cast<float4*>(s_a)[tid] =
        reinterpret_cast<const float4*>(za + (size_t)i0 * D_DIM)[tid];
  }
  if (tid < 4) s_esum[tid] = 0.0f;
  __syncthreads();

  const int wave = tid >> 6;
  const int lane = tid & 63;

  // x2 for the 4 A-rows: wave w (w<4) reduces row w
  if (wave < 4) {
    float v0 = s_a[wave * D_DIM + lane];
    float v1 = s_a[wave * D_DIM + lane + 64];
    float s = fmaf(v0, v0, v1 * v1);
#pragma unroll
    for (int m = 32; m >= 1; m >>= 1) s += __shfl_xor(s, m);
    if (lane == 0) s_x2[wave] = s;
  }
  __syncthreads();

  float x2v[4], rnxv[4];
#pragma unroll
  for (int i = 0; i < 4; ++i) {
    x2v[i] = s_x2[i];
    rnxv[i] = __frsqrt_rn(fmaxf(x2v[i], 1e-24f));
  }

  // lane decomposition: dg = D-slice (8 lanes cover a row, 16B each -> 128B
  // contiguous global segments), jg = which 4-j group within the wave
  const int dg = lane & 7;
  const int jg = lane >> 3;
  const int b0 = dg & 1, b1 = (dg >> 1) & 1, b2 = (dg >> 2) & 1;
  // after reduce-scatter, this lane holds pairs p = pbase, pbase+1 of the 4x4 tile
  const int pbase = (b0 << 3) | (b1 << 2) | (b2 << 1);
  const int isel = pbase >> 2;  // 0..3 (constant per lane across passes)
  const int jj0 = pbase & 3;    // 0 or 2

  const float x2i = b0 ? (b1 ? x2v[3] : x2v[2]) : (b1 ? x2v[1] : x2v[0]);
  const float rnxi = b0 ? (b1 ? rnxv[3] : rnxv[2]) : (b1 ? rnxv[1] : rnxv[0]);

  float my_esum = 0.0f;
  const float4* bp = reinterpret_cast<const float4*>(zb);

#pragma unroll
  for (int pass = 0; pass < 2; ++pass) {
    const int jb = pass * 512 + wave * 32 + jg * 4;

    float v[16];
    float y2p[4];
#pragma unroll
    for (int k = 0; k < 16; ++k) v[k] = 0.0f;
#pragma unroll
    for (int k = 0; k < 4; ++k) y2p[k] = 0.0f;

#pragma unroll
    for (int dstep = 0; dstep < 4; ++dstep) {
      const int dc = dstep * 8 + dg;
      float4 bv0 = bp[(jb + 0) * DCHUNKS + dc];
      float4 bv1 = bp[(jb + 1) * DCHUNKS + dc];
      float4 bv2 = bp[(jb + 2) * DCHUNKS + dc];
      float4 bv3 = bp[(jb + 3) * DCHUNKS + dc];
#pragma unroll
      for (int i = 0; i < 4; ++i) {
        float4 av = reinterpret_cast<const float4*>(s_a + i * D_DIM)[dc];
        v[i * 4 + 0] += dot4(av, bv0);
        v[i * 4 + 1] += dot4(av, bv1);
        v[i * 4 + 2] += dot4(av, bv2);
        v[i * 4 + 3] += dot4(av, bv3);
      }
      y2p[0] += dot4(bv0, bv0);
      y2p[1] += dot4(bv1, bv1);
      y2p[2] += dot4(bv2, bv2);
      y2p[3] += dot4(bv3, bv3);
    }

    // reduce-scatter y2: scatter by b2 first (each lane only needs the 2
    // columns it owns post-scatter), then butterfly over xor-1, xor-2.
    {
      float q0keep = b2 ? y2p[2] : y2p[0];
      float q0send = b2 ? y2p[0] : y2p[2];
      float q1keep = b2 ? y2p[3] : y2p[1];
      float q1send = b2 ? y2p[1] : y2p[3];
      y2p[0] = q0keep + __shfl_xor(q0send, 4);
      y2p[1] = q1keep + __shfl_xor(q1send, 4);
#pragma unroll
      for (int m = 1; m <= 2; m <<= 1) {
        y2p[0] += __shfl_xor(y2p[0], m);
        y2p[1] += __shfl_xor(y2p[1], m);
      }
    }
    const float y2s0 = y2p[0];
    const float y2s1 = y2p[1];

    // reduce-scatter the 16 dots over the 3 dg bits: 16 -> 8 -> 4 -> 2
    float w8[8];
#pragma unroll
    for (int k = 0; k < 8; ++k) {
      float mine = b0 ? v[8 + k] : v[k];
      float theirs = b0 ? v[k] : v[8 + k];
      w8[k] = mine + __shfl_xor(theirs, 1);
    }
    float w4[4];
#pragma unroll
    for (int k = 0; k < 4; ++k) {
      float mine = b1 ? w8[4 + k] : w8[k];
      float theirs = b1 ? w8[k] : w8[4 + k];
      w4[k] = mine + __shfl_xor(theirs, 2);
    }
    float w2[2];
#pragma unroll
    for (int k = 0; k < 2; ++k) {
      float mine = b2 ? w4[2 + k] : w4[k];
      float theirs = b2 ? w4[k] : w4[2 + k];
      w2[k] = mine + __shfl_xor(theirs, 4);
    }

#pragma unroll
    for (int pp = 0; pp < 2; ++pp) {
      const float g = (pp == 0) ? w2[0] : w2[1];
      const float y2 = (pp == 0) ? y2s0 : y2s1;
      const int gj = jb + jj0 + pp;
      const int gi = i0 + isel;

      const float xy = -g;  // x = -z_hyp[i]
      const float Am = fmaf(2.0f * K_C, xy, fmaf(K_C, y2, 1.0f));
      const float Bm = fmaf(-K_C, x2i, 1.0f);
      const float den =
          fmaxf(fmaf(2.0f * K_C, xy, fmaf(K_C * K_C * x2i, y2, 1.0f)), K_EPS);
      const float num2 =
          fmaf(Am * Am, x2i, fmaf(2.0f * Am * Bm, xy, Bm * Bm * y2));
      // t = min(sqrt_c*sqrt(num2)/den, 1-eps); log((1+t)/(1-t)) ==
      // log((den+u)/(den-u)) with u = min(sqrt_c*sqrt(num2), (1-eps)*den).
      // Single divide; den-u >= eps*den > 0 so no NaN path.
      const float u =
          fminf(K_SQRT_C * sqrtf(fmaxf(num2, 0.0f)), (1.0f - K_EPS) * den);
      const float dist = K_INV_SQRT_C * __logf(__fdividef(den + u, den - u));
      const float rny = __frsqrt_rn(fmaxf(y2, 1e-24f));
      const float comb = K_HALF_INV_T * fmaf(g * rnxi, rny, -dist);

      if (gi == gj) {
        s_pos[isel] = comb;  // unique writer across the whole block
      } else {
        my_esum += __expf(comb);
      }
    }
  }

  // reduce esum across jg groups (lanes with equal dg share isel)
#pragma unroll
  for (int m = 8; m <= 32; m <<= 1) my_esum += __shfl_xor(my_esum, m);
  if (jg == 0) atomicAdd(&s_esum[isel], my_esum);
  __syncthreads();

  // block partial: sum of its 4 row losses
  if (tid < 4) {
    s_rl[tid] = __logf(s_esum[tid]) - s_pos[tid];
  }
  __syncthreads();
  if (tid == 0) {
    // agent-scope release store: per-XCD L2s are not coherent (G16); make the
    // partial visible at the device coherent point before the grid barrier.
    __hip_atomic_store(&partials[blockIdx.x],
                       s_rl[0] + s_rl[1] + s_rl[2] + s_rl[3], __ATOMIC_RELEASE,
                       __HIP_MEMORY_SCOPE_AGENT);
  }

  cg::this_grid().sync();

  // block 0, wave 0: reduce the 256 block partials -> final loss
  if (blockIdx.x == 0 && tid < 64) {
    float v = __hip_atomic_load(&partials[tid], __ATOMIC_ACQUIRE,
                                __HIP_MEMORY_SCOPE_AGENT) +
              __hip_atomic_load(&partials[tid + 64], __ATOMIC_ACQUIRE,
                                __HIP_MEMORY_SCOPE_AGENT) +
              __hip_atomic_load(&partials[tid + 128], __ATOMIC_ACQUIRE,
                                __HIP_MEMORY_SCOPE_AGENT) +
              __hip_atomic_load(&partials[tid + 192], __ATOMIC_ACQUIRE,
                                __HIP_MEMORY_SCOPE_AGENT);
#pragma unroll
    for (int m = 32; m >= 1; m >>= 1) v += __shfl_xor(v, m);
    if (tid == 0) out[0] = v * (1.0f / 1024.0f);
  }
}

extern "C" void kernel_launch(void* const* d_in, const int* in_sizes, int n_in,
                              void* d_out, int out_size, void* d_ws, size_t ws_size,
                              hipStream_t stream) {
  const float* za = (const float*)d_in[0];
  const float* zb = (const float*)d_in[1];
  float* partials = (float*)d_ws;  // 256 floats
  float* outp = (float*)d_out;

  void* args[] = {(void*)&za, (void*)&zb, (void*)&partials, (void*)&outp};
  (void)hipLaunchCooperativeKernel((const void*)hypcd_pair, dim3(NBLOCKS),
                                   dim3(1024), args, 0, stream);
}

// Round 4
// 65.262 us; speedup vs baseline: 1.5806x; 1.5806x over previous
//
#include <hip/hip_runtime.h>
#include <math.h>

#define B_ROWS 1024
#define D_DIM 128
#define DCHUNKS 32  // float4 chunks per row

__device__ __forceinline__ float dot4(float4 a, float4 b) {
  return fmaf(a.x, b.x, fmaf(a.y, b.y, fmaf(a.z, b.z, a.w * b.w)));
}

// kC = 0.05, sqrt(c) = 0.223606..., 2/sqrt(c)*atanh -> (1/sqrt(c))*log form
// TEMP = 0.1, ALPHA_D = 0.5 -> comb = 5 * (cos_sim - dist)
#define K_C 0.05f
#define K_SQRT_C 0.22360679774997896f
#define K_INV_SQRT_C 4.47213595499958f
#define K_EPS 1e-6f
#define K_HALF_INV_T 5.0f

__global__ __launch_bounds__(1024) void hypcd_pair(const float* __restrict__ za,
                                                   const float* __restrict__ zb,
                                                   float* __restrict__ row_loss) {
  __shared__ float s_a[4 * D_DIM];
  __shared__ float s_x2[4];
  __shared__ float s_pos[4];
  __shared__ float s_esum[4];

  const int tid = threadIdx.x;
  const int i0 = blockIdx.x * 4;

  // stage the block's 4 A-rows (512 floats = 128 float4), coalesced
  if (tid < (4 * D_DIM / 4)) {
    reinterpret_cast<float4*>(s_a)[tid] =
        reinterpret_cast<const float4*>(za + (size_t)i0 * D_DIM)[tid];
  }
  if (tid < 4) s_esum[tid] = 0.0f;
  __syncthreads();

  const int wave = tid >> 6;
  const int lane = tid & 63;

  // x2 for the 4 A-rows: wave w (w<4) reduces row w
  if (wave < 4) {
    float v0 = s_a[wave * D_DIM + lane];
    float v1 = s_a[wave * D_DIM + lane + 64];
    float s = fmaf(v0, v0, v1 * v1);
#pragma unroll
    for (int m = 32; m >= 1; m >>= 1) s += __shfl_xor(s, m);
    if (lane == 0) s_x2[wave] = s;
  }
  __syncthreads();

  float x2v[4], rnxv[4];
#pragma unroll
  for (int i = 0; i < 4; ++i) {
    x2v[i] = s_x2[i];
    rnxv[i] = __frsqrt_rn(fmaxf(x2v[i], 1e-24f));
  }

  // lane decomposition: dg = D-slice (8 lanes cover a row, 16B each -> 128B
  // contiguous global segments), jg = which 4-j group within the wave
  const int dg = lane & 7;
  const int jg = lane >> 3;
  const int b0 = dg & 1, b1 = (dg >> 1) & 1, b2 = (dg >> 2) & 1;
  // after reduce-scatter, this lane holds pairs p = pbase, pbase+1 of the 4x4 tile
  const int pbase = (b0 << 3) | (b1 << 2) | (b2 << 1);
  const int isel = pbase >> 2;  // 0..3 (constant per lane across passes)
  const int jj0 = pbase & 3;    // 0 or 2

  const float x2i = b0 ? (b1 ? x2v[3] : x2v[2]) : (b1 ? x2v[1] : x2v[0]);
  const float rnxi = b0 ? (b1 ? rnxv[3] : rnxv[2]) : (b1 ? rnxv[1] : rnxv[0]);

  float my_esum = 0.0f;
  const float4* bp = reinterpret_cast<const float4*>(zb);

#pragma unroll
  for (int pass = 0; pass < 2; ++pass) {
    const int jb = pass * 512 + wave * 32 + jg * 4;

    float v[16];
    float y2p[4];
#pragma unroll
    for (int k = 0; k < 16; ++k) v[k] = 0.0f;
#pragma unroll
    for (int k = 0; k < 4; ++k) y2p[k] = 0.0f;

#pragma unroll
    for (int dstep = 0; dstep < 4; ++dstep) {
      const int dc = dstep * 8 + dg;
      float4 bv0 = bp[(jb + 0) * DCHUNKS + dc];
      float4 bv1 = bp[(jb + 1) * DCHUNKS + dc];
      float4 bv2 = bp[(jb + 2) * DCHUNKS + dc];
      float4 bv3 = bp[(jb + 3) * DCHUNKS + dc];
#pragma unroll
      for (int i = 0; i < 4; ++i) {
        float4 av = reinterpret_cast<const float4*>(s_a + i * D_DIM)[dc];
        v[i * 4 + 0] += dot4(av, bv0);
        v[i * 4 + 1] += dot4(av, bv1);
        v[i * 4 + 2] += dot4(av, bv2);
        v[i * 4 + 3] += dot4(av, bv3);
      }
      y2p[0] += dot4(bv0, bv0);
      y2p[1] += dot4(bv1, bv1);
      y2p[2] += dot4(bv2, bv2);
      y2p[3] += dot4(bv3, bv3);
    }

    // reduce-scatter y2: scatter by b2 first (each lane only needs the 2
    // columns it owns post-scatter), then butterfly over xor-1, xor-2.
    // 6 shuffles instead of the 12-shuffle full all-gather.
    {
      float q0keep = b2 ? y2p[2] : y2p[0];
      float q0send = b2 ? y2p[0] : y2p[2];
      float q1keep = b2 ? y2p[3] : y2p[1];
      float q1send = b2 ? y2p[1] : y2p[3];
      y2p[0] = q0keep + __shfl_xor(q0send, 4);
      y2p[1] = q1keep + __shfl_xor(q1send, 4);
#pragma unroll
      for (int m = 1; m <= 2; m <<= 1) {
        y2p[0] += __shfl_xor(y2p[0], m);
        y2p[1] += __shfl_xor(y2p[1], m);
      }
    }
    const float y2s0 = y2p[0];
    const float y2s1 = y2p[1];

    // reduce-scatter the 16 dots over the 3 dg bits: 16 -> 8 -> 4 -> 2
    float w8[8];
#pragma unroll
    for (int k = 0; k < 8; ++k) {
      float mine = b0 ? v[8 + k] : v[k];
      float theirs = b0 ? v[k] : v[8 + k];
      w8[k] = mine + __shfl_xor(theirs, 1);
    }
    float w4[4];
#pragma unroll
    for (int k = 0; k < 4; ++k) {
      float mine = b1 ? w8[4 + k] : w8[k];
      float theirs = b1 ? w8[k] : w8[4 + k];
      w4[k] = mine + __shfl_xor(theirs, 2);
    }
    float w2[2];
#pragma unroll
    for (int k = 0; k < 2; ++k) {
      float mine = b2 ? w4[2 + k] : w4[k];
      float theirs = b2 ? w4[k] : w4[2 + k];
      w2[k] = mine + __shfl_xor(theirs, 4);
    }

#pragma unroll
    for (int pp = 0; pp < 2; ++pp) {
      const float g = (pp == 0) ? w2[0] : w2[1];
      const float y2 = (pp == 0) ? y2s0 : y2s1;
      const int gj = jb + jj0 + pp;
      const int gi = i0 + isel;

      const float xy = -g;  // x = -z_hyp[i]
      const float Am = fmaf(2.0f * K_C, xy, fmaf(K_C, y2, 1.0f));
      const float Bm = fmaf(-K_C, x2i, 1.0f);
      const float den =
          fmaxf(fmaf(2.0f * K_C, xy, fmaf(K_C * K_C * x2i, y2, 1.0f)), K_EPS);
      const float num2 =
          fmaf(Am * Am, x2i, fmaf(2.0f * Am * Bm, xy, Bm * Bm * y2));
      // t = min(sqrt_c*sqrt(num2)/den, 1-eps); log((1+t)/(1-t)) ==
      // log((den+u)/(den-u)) with u = min(sqrt_c*sqrt(num2), (1-eps)*den).
      // Single divide; den-u >= eps*den > 0 so no NaN path.
      const float u =
          fminf(K_SQRT_C * sqrtf(fmaxf(num2, 0.0f)), (1.0f - K_EPS) * den);
      const float dist = K_INV_SQRT_C * __logf(__fdividef(den + u, den - u));
      const float rny = __frsqrt_rn(fmaxf(y2, 1e-24f));
      const float comb = K_HALF_INV_T * fmaf(g * rnxi, rny, -dist);

      if (gi == gj) {
        s_pos[isel] = comb;  // unique writer across the whole block
      } else {
        my_esum += __expf(comb);
      }
    }
  }

  // reduce esum across jg groups (lanes with equal dg share isel)
#pragma unroll
  for (int m = 8; m <= 32; m <<= 1) my_esum += __shfl_xor(my_esum, m);
  if (jg == 0) atomicAdd(&s_esum[isel], my_esum);
  __syncthreads();

  if (tid < 4) {
    row_loss[i0 + tid] = __logf(s_esum[tid]) - s_pos[tid];
  }
}

__global__ __launch_bounds__(256) void hypcd_reduce(const float* __restrict__ row_loss,
                                                    float* __restrict__ out) {
  __shared__ float s[4];
  const int tid = threadIdx.x;
  float v = row_loss[tid] + row_loss[tid + 256] + row_loss[tid + 512] +
            row_loss[tid + 768];
#pragma unroll
  for (int m = 32; m >= 1; m >>= 1) v += __shfl_xor(v, m);
  if ((tid & 63) == 0) s[tid >> 6] = v;
  __syncthreads();
  if (tid == 0) out[0] = (s[0] + s[1] + s[2] + s[3]) * (1.0f / 1024.0f);
}

extern "C" void kernel_launch(void* const* d_in, const int* in_sizes, int n_in,
                              void* d_out, int out_size, void* d_ws, size_t ws_size,
                              hipStream_t stream) {
  const float* za = (const float*)d_in[0];
  const float* zb = (const float*)d_in[1];
  float* row_loss = (float*)d_ws;  // 1024 floats

  hypcd_pair<<<B_ROWS / 4, 1024, 0, stream>>>(za, zb, row_loss);
  hypcd_reduce<<<1, 256, 0, stream>>>(row_loss, (float*)d_out);
}